// Round 1
// baseline (157.745 us; speedup 1.0000x reference)
//
#include <hip/hip_runtime.h>
#include <hip/hip_bf16.h>

// Attention B=4,N=2048,D=384,H=8,DH=48 — Round 15:
//  - attn: K-split x2 (grid 32x16x2 -> 4 blocks/CU, 4 waves/SIMD),
//    double-buffered LDS with ONE barrier per ktile, setprio around MFMAs.
//    Blocks emit f32 partial O + partial l; new combine kernel normalizes.
//  - qkv/proj/prep unchanged from R14.

typedef _Float16 f16x8 __attribute__((ext_vector_type(8)));
typedef _Float16 f16x4 __attribute__((ext_vector_type(4)));
typedef float    f32x4 __attribute__((ext_vector_type(4)));
typedef float    f32x16 __attribute__((ext_vector_type(16)));

// scale * log2(e) = 48^-0.5 * 1.4426950408889634
#define QSCL 0.20822035963448658f

// ---------------------------------------------------------------------------
// prep: blocks 0..143 transpose weights (LDS-tiled); 144..399 convert x->f16
// ---------------------------------------------------------------------------
__global__ __launch_bounds__(256) void prep(const float4* __restrict__ x,
                                            const float* __restrict__ wq,
                                            const float* __restrict__ wp,
                                            f16x4* __restrict__ xh4,
                                            _Float16* __restrict__ wqt,
                                            _Float16* __restrict__ wpt)
{
    __shared__ _Float16 t[64][65];
    const int blk = blockIdx.x, tid = threadIdx.x;
    if (blk < 144) {
        const float* src; _Float16* dst; int Nn, k0, n0;
        if (blk < 108) {            // Wqkv: 6 k-tiles x 18 n-tiles
            src = wq; dst = wqt; Nn = 1152;
            k0 = (blk % 6) * 64; n0 = (blk / 6) * 64;
        } else {                    // Wproj: 6 x 6
            const int b2 = blk - 108;
            src = wp; dst = wpt; Nn = 384;
            k0 = (b2 % 6) * 64; n0 = (b2 / 6) * 64;
        }
        #pragma unroll
        for (int i = 0; i < 16; i++) {
            const int id = tid + i * 256;
            const int k = id >> 6, n = id & 63;      // coalesced over n
            t[k][n] = (_Float16)src[(size_t)(k0 + k) * Nn + n0 + n];
        }
        __syncthreads();
        #pragma unroll
        for (int i = 0; i < 16; i++) {
            const int id = tid + i * 256;
            const int n = id >> 6, k = id & 63;      // coalesced over k
            dst[(size_t)(n0 + n) * 384 + k0 + k] = t[k][n];
        }
    } else {
        const int base = (blk - 144) * 3072;         // 256 blocks x 3072 = 786432
        #pragma unroll
        for (int r = 0; r < 12; r++) {
            const int j = base + r * 256 + tid;
            const float4 tt = x[j];
            f16x4 hh;
            hh[0] = (_Float16)tt.x; hh[1] = (_Float16)tt.y;
            hh[2] = (_Float16)tt.z; hh[3] = (_Float16)tt.w;
            xh4[j] = hh;
        }
    }
}

// ---------------------------------------------------------------------------
// QKV GEMM: A = xh[8192][384] f16, Bt = wqkvt[1152][384] f16.
// 128x128 tile, BK=32, padded LDS (stride 40), 16x16x32 MFMA, 4 waves,
// reg-prefetch. Epilogue via LDS transpose -> coalesced f16x8 stores.
// ---------------------------------------------------------------------------
union QkvSmem {
    struct { _Float16 As[128][40]; _Float16 Bs[128][40]; } g;  // 20480 B
    _Float16 Ts[128][136];   // V transpose   [col][n]   34816 B
    _Float16 Ts2[128][136];  // q/k transpose [row][col] 34816 B
};

__global__ __launch_bounds__(256) void qkv_f16(const _Float16* __restrict__ A,
                                               const _Float16* __restrict__ Bt,
                                               _Float16* __restrict__ qh,
                                               _Float16* __restrict__ kh,
                                               _Float16* __restrict__ vt)
{
    __shared__ QkvSmem sm;
    const int tid = threadIdx.x;
    const int w = tid >> 6, lane = tid & 63, cl = lane & 15, quad = lane >> 4;
    const int bm = blockIdx.x, bn = blockIdx.y;

    f32x4 acc[2][8];
    const f32x4 z4 = {0.f, 0.f, 0.f, 0.f};
    #pragma unroll
    for (int mi = 0; mi < 2; mi++)
        #pragma unroll
        for (int t = 0; t < 8; t++) acc[mi][t] = z4;

    const int ar = tid >> 2, ac = (tid & 3) * 8;     // 512 chunks: 2/thread
    const _Float16* Ag = A  + (size_t)(bm * 128 + ar) * 384 + ac;
    const _Float16* Bg = Bt + (size_t)(bn * 128 + ar) * 384 + ac;

    f16x8 pa[2], pb[2];
    #pragma unroll
    for (int j = 0; j < 2; j++) {
        pa[j] = *(const f16x8*)(Ag + (size_t)(64 * j) * 384);
        pb[j] = *(const f16x8*)(Bg + (size_t)(64 * j) * 384);
    }

    for (int k0 = 0; k0 < 384; k0 += 32) {
        __syncthreads();
        #pragma unroll
        for (int j = 0; j < 2; j++) {
            *(f16x8*)&sm.g.As[ar + 64 * j][ac] = pa[j];
            *(f16x8*)&sm.g.Bs[ar + 64 * j][ac] = pb[j];
        }
        __syncthreads();
        if (k0 + 32 < 384) {
            #pragma unroll
            for (int j = 0; j < 2; j++) {
                pa[j] = *(const f16x8*)(Ag + (size_t)(64 * j) * 384 + k0 + 32);
                pb[j] = *(const f16x8*)(Bg + (size_t)(64 * j) * 384 + k0 + 32);
            }
        }
        f16x8 bf[8];
        #pragma unroll
        for (int t = 0; t < 8; t++)
            bf[t] = *(const f16x8*)&sm.g.Bs[t * 16 + cl][quad * 8];
        #pragma unroll
        for (int mi = 0; mi < 2; mi++) {
            const f16x8 af = *(const f16x8*)&sm.g.As[w * 32 + mi * 16 + cl][quad * 8];
            #pragma unroll
            for (int t = 0; t < 8; t++)
                acc[mi][t] = __builtin_amdgcn_mfma_f32_16x16x32_f16(af, bf[t], acc[mi][t], 0, 0, 0);
        }
    }

    const int s = (bn * 128) / 384;    // uniform per block (384 % 128 == 0)
    const int b  = (bm * 128) >> 11;
    const int n0 = (bm * 128) & 2047;
    if (s == 2) {
        // ---- V: LDS transpose [col][n] -> coalesced stores along n ----
        __syncthreads();
        #pragma unroll
        for (int t = 0; t < 8; t++)
            #pragma unroll
            for (int mi = 0; mi < 2; mi++)
                #pragma unroll
                for (int r = 0; r < 4; r++)
                    sm.Ts[t * 16 + cl][w * 32 + mi * 16 + quad * 4 + r] =
                        (_Float16)acc[mi][t][r];
        __syncthreads();
        const int colbase = bn * 128 - 768;      // 0,128,256
        #pragma unroll
        for (int i = 0; i < 8; i++) {
            const int c = i * 256 + tid;         // 0..2047 chunks of 8
            const int col = c >> 4, nc = c & 15;
            const int gcol = colbase + col;
            const int head = gcol / 48, d = gcol - head * 48;
            const int bh = b * 8 + head;
            *(f16x8*)&vt[(size_t)(bh * 48 + d) * 2048 + n0 + nc * 8] =
                *(const f16x8*)&sm.Ts[col][nc * 8];
        }
    } else {
        // ---- q/k: LDS transpose [row][col] -> coalesced f16x8 stores ----
        __syncthreads();
        const float scl = (s == 0) ? QSCL : 1.0f;
        #pragma unroll
        for (int t = 0; t < 8; t++)
            #pragma unroll
            for (int mi = 0; mi < 2; mi++)
                #pragma unroll
                for (int r = 0; r < 4; r++)
                    sm.Ts2[w * 32 + mi * 16 + quad * 4 + r][t * 16 + cl] =
                        (_Float16)(acc[mi][t][r] * scl);
        __syncthreads();
        _Float16* dst = (s == 0) ? qh : kh;
        const int colbase = bn * 128 - s * 384;  // 0,128,256
        #pragma unroll
        for (int i = 0; i < 8; i++) {
            const int c = i * 256 + tid;         // 0..2047 chunks of 8
            const int row = c >> 4, ch = c & 15;
            const int gcol = colbase + ch * 8;   // multiple of 8; 48=6x8 -> no straddle
            const int head = gcol / 48, d = gcol - head * 48;
            const int bh = b * 8 + head;
            *(f16x8*)&dst[(size_t)(bh * 2048 + n0 + row) * 48 + d] =
                *(const f16x8*)&sm.Ts2[row][ch * 8];
        }
    }
}

// ---------------------------------------------------------------------------
// Flash attention (R15): K-split x2 via blockIdx.z; each block does 1024 keys.
// 32x32x16 f16 MFMA, no-max softmax, register-P via kappa key-permutation;
// l via ones-row 48. Double-buffered LDS, ONE barrier per ktile, setprio.
// Outputs: f32 partial O [sp][b][q][hd*48+d] and partial l [sp][bh][q].
// ---------------------------------------------------------------------------
union AttnSmem {
    struct {
        _Float16 Ks[2][64][56];    // [buf][key][dh]        14336 B
        _Float16 Vts[2][64][72];   // [buf][dh][key-slot]   18432 B; row 48 ones
    } a;                           // 32768 B
    float Otf[128][52];            // epilogue transpose [q][dh] 26624 B
};

__global__ __launch_bounds__(256) void attn_f16(const _Float16* __restrict__ qh,
                                                const _Float16* __restrict__ kh,
                                                const _Float16* __restrict__ vt,
                                                float* __restrict__ opart,
                                                float* __restrict__ lpart)
{
    __shared__ AttnSmem sm;
    const int tid = threadIdx.x;
    const int w = tid >> 6, lane = tid & 63, ln = lane & 31, h = lane >> 5;
    const int bh = blockIdx.x, qt = blockIdx.y, sp = blockIdx.z;

    // one-time: Vts rows 48..63 for BOTH buffers (48 = ones for l, rest zero)
    for (int i = tid; i < 2 * 16 * 72; i += 256) {
        const int bi = i / (16 * 72), j = i - bi * (16 * 72);
        const int r = 48 + j / 72, c = j - (j / 72) * 72;
        sm.a.Vts[bi][r][c] = (r == 48) ? (_Float16)1.0f : (_Float16)0.0f;
    }

    // Q B-frags (3, dh = 16i + 8h + 0..7), query = qt*128 + w*32 + ln
    f16x8 qf[3];
    {
        const _Float16* qp = qh + (size_t)(bh * 2048 + qt * 128 + w * 32 + ln) * 48 + 8 * h;
        qf[0] = *(const f16x8*)qp;
        qf[1] = *(const f16x8*)(qp + 16);
        qf[2] = *(const f16x8*)(qp + 32);
    }

    f32x16 o0, o1;
    #pragma unroll
    for (int r = 0; r < 16; r++) { o0[r] = 0.f; o1[r] = 0.f; }

    // key range for this split: [sp*1024, sp*1024 + 1024)
    const _Float16* kbase = kh + (size_t)bh * 2048 * 48 + (size_t)sp * 1024 * 48;
    const _Float16* vbase = vt + (size_t)bh * 48 * 2048 + sp * 1024;

    const int kr0 = tid / 6,         kc0 = (tid % 6) * 8;
    const int kid1 = tid + 256;
    const int kr1 = kid1 / 6,        kc1 = (kid1 % 6) * 8;
    const int vr0 = tid >> 3,        vc0 = (tid & 7) * 8;
    const int vr1 = (tid + 256) >> 3;
    const int vslot_lo = 16 * ((tid & 7) >> 1) + 4 * (tid & 1);
    const _Float16* ks0 = kbase + (size_t)kr0 * 48 + kc0;
    const _Float16* ks1 = kbase + (size_t)kr1 * 48 + kc1;
    const _Float16* vs0 = vbase + (size_t)vr0 * 2048 + vc0;
    const _Float16* vs1 = vbase + (size_t)vr1 * 2048 + vc0;

    f16x8 rk0 = *(const f16x8*)ks0;
    f16x8 rv0 = *(const f16x8*)vs0;
    f16x8 rk1, rv1;
    if (tid < 128) { rk1 = *(const f16x8*)ks1; rv1 = *(const f16x8*)vs1; }

    for (int t = 0; t < 16; ++t) {
        _Float16 (*Ksb)[56] = sm.a.Ks[t & 1];
        _Float16 (*Vtb)[72] = sm.a.Vts[t & 1];

        // ---- stage regs -> LDS[buf] ----
        *(f16x8*)&Ksb[kr0][kc0] = rk0;
        {
            const f16x4* rvh = (const f16x4*)&rv0;
            *(f16x4*)&Vtb[vr0][vslot_lo]     = rvh[0];
            *(f16x4*)&Vtb[vr0][vslot_lo + 8] = rvh[1];
        }
        if (tid < 128) {
            *(f16x8*)&Ksb[kr1][kc1] = rk1;
            const f16x4* rvh = (const f16x4*)&rv1;
            *(f16x4*)&Vtb[vr1][vslot_lo]     = rvh[0];
            *(f16x4*)&Vtb[vr1][vslot_lo + 8] = rvh[1];
        }
        __syncthreads();   // single barrier/iter: dbuf covers write-after-read

        // ---- prefetch next ktile into regs (consumed next iteration) ----
        if (t < 15) {
            const int off = (t + 1) * 64;
            rk0 = *(const f16x8*)(ks0 + (size_t)off * 48);
            rv0 = *(const f16x8*)(vs0 + off);
            if (tid < 128) {
                rk1 = *(const f16x8*)(ks1 + (size_t)off * 48);
                rv1 = *(const f16x8*)(vs1 + off);
            }
        }

        // ---- S^T = K.Q^T : C[key][query], regs = keys (r&3)+8(r>>2)+4h ----
        f32x16 s0, s1;
        #pragma unroll
        for (int r = 0; r < 16; r++) { s0[r] = 0.f; s1[r] = 0.f; }
        __builtin_amdgcn_s_setprio(1);
        #pragma unroll
        for (int i = 0; i < 3; i++) {
            const f16x8 ka0 = *(const f16x8*)&Ksb[ln][16 * i + 8 * h];
            s0 = __builtin_amdgcn_mfma_f32_32x32x16_f16(ka0, qf[i], s0, 0, 0, 0);
            const f16x8 ka1 = *(const f16x8*)&Ksb[32 + ln][16 * i + 8 * h];
            s1 = __builtin_amdgcn_mfma_f32_32x32x16_f16(ka1, qf[i], s1, 0, 0, 0);
        }
        __builtin_amdgcn_s_setprio(0);

        // ---- P = exp2(S^T) packed directly as PV B-frags (no LDS) ----
        f16x8 pbf[4];
        #pragma unroll
        for (int j = 0; j < 8; j++) {
            pbf[0][j] = (_Float16)exp2f(s0[j]);
            pbf[1][j] = (_Float16)exp2f(s0[8 + j]);
            pbf[2][j] = (_Float16)exp2f(s1[j]);
            pbf[3][j] = (_Float16)exp2f(s1[8 + j]);
        }

        // ---- O^T += V^T.P^T : A = permuted Vts frags, B = pbf ----
        __builtin_amdgcn_s_setprio(1);
        #pragma unroll
        for (int c = 0; c < 4; c++) {
            const f16x8 av0 = *(const f16x8*)&Vtb[ln][16 * c + 8 * h];
            o0 = __builtin_amdgcn_mfma_f32_32x32x16_f16(av0, pbf[c], o0, 0, 0, 0);
            const f16x8 av1 = *(const f16x8*)&Vtb[32 + ln][16 * c + 8 * h];
            o1 = __builtin_amdgcn_mfma_f32_32x32x16_f16(av1, pbf[c], o1, 0, 0, 0);
        }
        __builtin_amdgcn_s_setprio(0);
    }

    // ---- partial l = O^T row 48 = o1 reg 8 on h=0 lanes (their query = ln) ----
    if (h == 0)
        lpart[((size_t)sp * 32 + bh) * 2048 + qt * 128 + w * 32 + ln] = o1[8];

    // ---- epilogue: O^T -> LDS transpose (f32, unnormalized) -> opart ----
    __syncthreads();
    #pragma unroll
    for (int r = 0; r < 16; r++)
        sm.Otf[w * 32 + ln][(r & 3) + 8 * (r >> 2) + 4 * h] = o0[r];
    #pragma unroll
    for (int r = 0; r < 8; r++)
        sm.Otf[w * 32 + ln][32 + (r & 3) + 8 * (r >> 2) + 4 * h] = o1[r];
    __syncthreads();
    const int b = bh >> 3, hd = bh & 7;
    #pragma unroll
    for (int i = 0; i < 6; i++) {
        const int c2 = i * 256 + tid;            // 0..1535; 128 rows x 12 f32x4
        const int row = c2 / 12, ch = c2 % 12;
        const int q = qt * 128 + row;
        *(f32x4*)&opart[((size_t)sp * 8192 + b * 2048 + q) * 384 + hd * 48 + ch * 4] =
            *(const f32x4*)&sm.Otf[row][ch * 4];
    }
}

// ---------------------------------------------------------------------------
// combine: ab[row][col] = (o0 + o1) / (l0 + l1), f32 -> f16.
// One thread per 8 outputs; fully coalesced.
// ---------------------------------------------------------------------------
__global__ __launch_bounds__(256) void comb(const float* __restrict__ opart,
                                            const float* __restrict__ lpart,
                                            _Float16* __restrict__ ab)
{
    const int c = blockIdx.x * 256 + threadIdx.x;   // 0..393215
    const int row = c / 48, ch = c - row * 48;      // row = b*2048+q, col = ch*8
    const int b = row >> 11, q = row & 2047;
    const int hd = ch / 6;                          // (ch*8)/48
    const size_t SP = (size_t)8192 * 384;
    const float* p0 = opart + (size_t)row * 384 + ch * 8;
    const f32x4 a0 = *(const f32x4*)p0;
    const f32x4 a1 = *(const f32x4*)(p0 + 4);
    const f32x4 b0 = *(const f32x4*)(p0 + SP);
    const f32x4 b1 = *(const f32x4*)(p0 + SP + 4);
    const int bh = b * 8 + hd;
    const float l0 = lpart[(size_t)bh * 2048 + q];
    const float l1 = lpart[(size_t)(32 + bh) * 2048 + q];
    const float inv = 1.f / (l0 + l1);
    f16x8 o;
    #pragma unroll
    for (int j = 0; j < 4; j++) {
        o[j]     = (_Float16)((a0[j] + b0[j]) * inv);
        o[4 + j] = (_Float16)((a1[j] + b1[j]) * inv);
    }
    *(f16x8*)&ab[(size_t)row * 384 + ch * 8] = o;
}

// ---------------------------------------------------------------------------
// Proj GEMM: A = ab[8192][384] f16, Bt = wprojt[384][384] f16, +bias -> fp32
// 64x64 tile, BK=64, padded LDS, reg-prefetch.
// ---------------------------------------------------------------------------
__global__ __launch_bounds__(256) void proj_f16(const _Float16* __restrict__ A,
                                                const _Float16* __restrict__ Bt,
                                                const float* __restrict__ bias,
                                                float* __restrict__ out)
{
    __shared__ _Float16 As[64][72];
    __shared__ _Float16 Bs[64][72];
    const int tid = threadIdx.x;
    const int w = tid >> 6, lane = tid & 63, cl = lane & 15, quad = lane >> 4;
    const int bm = blockIdx.x, bn = blockIdx.y;

    f32x4 acc[4];
    const f32x4 z4 = {0.f, 0.f, 0.f, 0.f};
    #pragma unroll
    for (int t = 0; t < 4; t++) acc[t] = z4;

    const int ar = tid >> 3, ac = (tid & 7) * 8;
    const _Float16* Ag = A  + (size_t)(bm * 64 + ar) * 384 + ac;
    const _Float16* Bg = Bt + (size_t)(bn * 64 + ar) * 384 + ac;

    f16x8 pa[2], pb[2];
    #pragma unroll
    for (int j = 0; j < 2; j++) {
        pa[j] = *(const f16x8*)(Ag + (size_t)(32 * j) * 384);
        pb[j] = *(const f16x8*)(Bg + (size_t)(32 * j) * 384);
    }

    for (int k0 = 0; k0 < 384; k0 += 64) {
        __syncthreads();
        #pragma unroll
        for (int j = 0; j < 2; j++) {
            *(f16x8*)&As[ar + 32 * j][ac] = pa[j];
            *(f16x8*)&Bs[ar + 32 * j][ac] = pb[j];
        }
        __syncthreads();
        if (k0 + 64 < 384) {
            #pragma unroll
            for (int j = 0; j < 2; j++) {
                pa[j] = *(const f16x8*)(Ag + (size_t)(32 * j) * 384 + k0 + 64);
                pb[j] = *(const f16x8*)(Bg + (size_t)(32 * j) * 384 + k0 + 64);
            }
        }
        #pragma unroll
        for (int kh2 = 0; kh2 < 2; kh2++) {
            const f16x8 af = *(const f16x8*)&As[w * 16 + cl][kh2 * 32 + quad * 8];
            #pragma unroll
            for (int t = 0; t < 4; t++) {
                const f16x8 bf = *(const f16x8*)&Bs[t * 16 + cl][kh2 * 32 + quad * 8];
                acc[t] = __builtin_amdgcn_mfma_f32_16x16x32_f16(af, bf, acc[t], 0, 0, 0);
            }
        }
    }

    #pragma unroll
    for (int t = 0; t < 4; t++) {
        const int col = bn * 64 + t * 16 + cl;
        const float bv = bias[col];
        #pragma unroll
        for (int r = 0; r < 4; r++) {
            const int row = bm * 64 + w * 16 + quad * 4 + r;
            out[(size_t)row * 384 + col] = acc[t][r] + bv;
        }
    }
}

// ---------------------------------------------------------------------------
extern "C" void kernel_launch(void* const* d_in, const int* in_sizes, int n_in,
                              void* d_out, int out_size, void* d_ws, size_t ws_size,
                              hipStream_t stream) {
    const float* x     = (const float*)d_in[0];  // [4,2048,384]
    const float* Wqkv  = (const float*)d_in[1];  // [384,1152]
    const float* Wproj = (const float*)d_in[2];  // [384,384]
    const float* bproj = (const float*)d_in[3];  // [384]
    float* out = (float*)d_out;

    char* ws = (char*)d_ws;
    // persistent regions
    _Float16* qh     = (_Float16*)(ws + 0);          // 32*2048*48*2 = 6,291,456
    _Float16* kh     = (_Float16*)(ws + 6291456);    // 6,291,456
    _Float16* vt     = (_Float16*)(ws + 12582912);   // 6,291,456
    _Float16* ab     = (_Float16*)(ws + 18874368);   // 6,291,456
    _Float16* wprojt = (_Float16*)(ws + 25165824);   // 384*384*2   =   294,912
    float*    lpart  = (float*)   (ws + 25460736);   // 2*32*2048*4 =   524,288
    float*    opart  = (float*)   (ws + 25985024);   // 2*8192*384*4 = 25,165,824
    // aliased over opart (xh/wqkvt are dead before attn writes opart):
    _Float16* xh     = (_Float16*)(ws + 25985024);   // 8192*384*2  = 6,291,456
    _Float16* wqkvt  = (_Float16*)(ws + 32276480);   // 1152*384*2  =   884,736
    // total ws use: 51,150,848 B

    prep<<<400, 256, 0, stream>>>((const float4*)x, Wqkv, Wproj,
                                  (f16x4*)xh, wqkvt, wprojt);
    qkv_f16<<<dim3(64, 9), 256, 0, stream>>>(xh, wqkvt, qh, kh, vt);
    attn_f16<<<dim3(32, 16, 2), 256, 0, stream>>>(qh, kh, vt, opart, lpart);
    comb<<<1536, 256, 0, stream>>>(opart, lpart, ab);
    proj_f16<<<dim3(128, 6), 256, 0, stream>>>(ab, wprojt, bproj, out);
}